// Round 2
// baseline (303.659 us; speedup 1.0000x reference)
//
#include <hip/hip_runtime.h>
#include <hip/hip_bf16.h>
#include <stdint.h>

#define T_SZ 2048
#define B_SZ 64
#define H_SZ 256
#define I_SZ 256
#define M_SZ (B_SZ * T_SZ)          // 131072
#define TBH  (T_SZ * B_SZ * H_SZ)   // 33554432

typedef float f32x4 __attribute__((ext_vector_type(4)));
typedef short s16x8 __attribute__((ext_vector_type(8)));

// RTNE fp32 -> bf16 pair packed into one u32 (low = a, high = b)
__device__ __forceinline__ unsigned pack_bf16(float a, float b) {
    unsigned ua = __float_as_uint(a);
    unsigned ub = __float_as_uint(b);
    ua += 0x7fffu + ((ua >> 16) & 1u);
    ub += 0x7fffu + ((ub >> 16) & 1u);
    return (ua >> 16) | (ub & 0xffff0000u);
}

__device__ __forceinline__ s16x8 pack8(float4 lo, float4 hi) {
    union { uint4 u; s16x8 v; } cv;
    cv.u.x = pack_bf16(lo.x, lo.y);
    cv.u.y = pack_bf16(lo.z, lo.w);
    cv.u.z = pack_bf16(hi.x, hi.y);
    cv.u.w = pack_bf16(hi.z, hi.w);
    return cv.v;
}

// async 16B global -> LDS (wave-uniform LDS base, lane writes base + lane*16)
__device__ __forceinline__ void gload_lds16(const unsigned short* g, unsigned short* l) {
    __builtin_amdgcn_global_load_lds(
        (const __attribute__((address_space(1))) unsigned int*)g,
        (__attribute__((address_space(3))) unsigned int*)l,
        16, 0, 0);
}

// ---------------------------------------------------------------------------
// prep: gb[b,h] = sum_j h0[b,j]*W_fh[h,j] + b_fi[h] + b_fh[h]
//       + convert W_fi (fp32 HxI) -> bf16 into Wb
// ---------------------------------------------------------------------------
__global__ void prep_kernel(const float* __restrict__ h0,
                            const float* __restrict__ W_fi,
                            const float* __restrict__ b_fi,
                            const float* __restrict__ W_fh,
                            const float* __restrict__ b_fh,
                            unsigned short* __restrict__ Wb,
                            float* __restrict__ gb) {
    __shared__ float h0s[H_SZ];
    const int b = blockIdx.x;
    const int h = threadIdx.x;
    h0s[h] = h0[b * H_SZ + h];
    __syncthreads();
    const float4* w4 = (const float4*)(W_fh + (size_t)h * H_SZ);
    float acc = 0.f;
#pragma unroll 16
    for (int j = 0; j < H_SZ / 4; ++j) {
        float4 w = w4[j];
        acc = fmaf(w.x, h0s[4 * j + 0], acc);
        acc = fmaf(w.y, h0s[4 * j + 1], acc);
        acc = fmaf(w.z, h0s[4 * j + 2], acc);
        acc = fmaf(w.w, h0s[4 * j + 3], acc);
    }
    gb[b * H_SZ + h] = acc + b_fi[h] + b_fh[h];

    const int e = (b * 256 + h) * 4;
    float4 wv = *(const float4*)(W_fi + e);
    uint2 pk;
    pk.x = pack_bf16(wv.x, wv.y);
    pk.y = pack_bf16(wv.z, wv.w);
    *(uint2*)(Wb + e) = pk;
}

// ---------------------------------------------------------------------------
// main v2: B-tile (64 N-rows x 256 K, bf16) staged to LDS ONCE per block with
// XOR chunk swizzle; A streamed global->register MFMA fragments (no LDS, no
// K-loop barriers). 4096 blocks = 4 N-tiles x 1024 M-tiles(128 rows).
// Each wave: 32 M-rows x 64 N-cols, acc[2][4].
// ---------------------------------------------------------------------------
__global__ __launch_bounds__(256, 4) void lstm_main(
    const float* __restrict__ x,
    const unsigned short* __restrict__ Wb,
    const float* __restrict__ gb,
    const float* __restrict__ c0,
    float* __restrict__ out) {
    // Bs[row][chunk]: 64 rows x 32 chunks x 16B = 32 KB.
    // Physical chunk p holds logical k-chunk kc = p ^ (row & 7).
    __shared__ __align__(16) unsigned short Bs[64 * 256];

    const int tid  = threadIdx.x;
    const int lane = tid & 63;
    const int wid  = tid >> 6;
    const int bid  = blockIdx.x;
    const int n0 = (bid & 3) * 64;        // nt fastest -> x-slab shared by 4 live blocks
    const int m0 = (bid >> 2) * 128;

    // ---- stage B tile: 2048 chunks, 8 global_load_lds issues per wave ----
#pragma unroll
    for (int i = 0; i < 8; ++i) {
        const int cbase = wid * 512 + i * 64;
        const int c = cbase + lane;
        const int row = c >> 5;
        const int kc = (lane & 31) ^ (row & 7);   // swizzled source chunk
        gload_lds16(Wb + (((size_t)(n0 + row)) << 8) + (kc << 3),
                    Bs + (size_t)cbase * 8);
    }

    const int fr = lane & 15, fq = lane >> 4;

    f32x4 acc[2][4];
#pragma unroll
    for (int mi = 0; mi < 2; ++mi)
#pragma unroll
        for (int ni = 0; ni < 4; ++ni)
            acc[mi][ni] = (f32x4){0.f, 0.f, 0.f, 0.f};

    // A fragment pointers: lane holds A[m = fr][k = fq*8 .. +7]
    const float* a0 = x + (size_t)(m0 + wid * 32 + fr) * I_SZ + fq * 8;
    const float* a1 = a0 + 16 * I_SZ;

    // preload kt=0 (overlaps with B staging; barrier drains all)
    float4 p00 = *(const float4*)a0;
    float4 p01 = *(const float4*)(a0 + 4);
    float4 p10 = *(const float4*)a1;
    float4 p11 = *(const float4*)(a1 + 4);

    __syncthreads();   // B resident; ONLY barrier in the kernel

#pragma unroll
    for (int kt = 0; kt < 8; ++kt) {
        s16x8 af0 = pack8(p00, p01);
        s16x8 af1 = pack8(p10, p11);
        if (kt < 7) {  // prefetch next K-slice
            const int ko = (kt + 1) * 32;
            p00 = *(const float4*)(a0 + ko);
            p01 = *(const float4*)(a0 + ko + 4);
            p10 = *(const float4*)(a1 + ko);
            p11 = *(const float4*)(a1 + ko + 4);
        }
        s16x8 bf[4];
#pragma unroll
        for (int ni = 0; ni < 4; ++ni) {
            const int nl = ni * 16 + fr;
            const int p = (kt * 4 + fq) ^ (nl & 7);   // de-swizzle
            bf[ni] = *(const s16x8*)(Bs + nl * 256 + p * 8);
        }
#pragma unroll
        for (int ni = 0; ni < 4; ++ni) {
            acc[0][ni] = __builtin_amdgcn_mfma_f32_16x16x32_bf16(af0, bf[ni], acc[0][ni], 0, 0, 0);
            acc[1][ni] = __builtin_amdgcn_mfma_f32_16x16x32_bf16(af1, bf[ni], acc[1][ni], 0, 0, 0);
        }
    }

    // ---- fused epilogue: C/D layout col=lane&15, row=(lane>>4)*4+reg ----
    const int hbase = n0 + fr;
#pragma unroll
    for (int mi = 0; mi < 2; ++mi) {
#pragma unroll
        for (int r = 0; r < 4; ++r) {
            const int Mg = m0 + wid * 32 + mi * 16 + fq * 4 + r;
            const int bb = Mg >> 11;           // / T
            const int tt = Mg & (T_SZ - 1);    // % T
            float* orow = out + (size_t)tt * (B_SZ * H_SZ) + bb * H_SZ;
            const float* gbrow = gb + bb * H_SZ;
            const float* c0row = c0 + bb * H_SZ;
            const bool last = (tt == T_SZ - 1);
#pragma unroll
            for (int ni = 0; ni < 4; ++ni) {
                const int h = hbase + ni * 16;
                float g = acc[mi][ni][r] + gbrow[h];
                float e = __expf(-g);
                float s = __builtin_amdgcn_rcpf(1.f + e);               // sigmoid(g)
                float e2 = e * e;
                float m = (1.f - e2) * __builtin_amdgcn_rcpf(1.f + e2); // tanh(g)
                float cv = s * (c0row[h] + m);
                float ec = __expf(-2.f * cv);
                float th = (1.f - ec) * __builtin_amdgcn_rcpf(1.f + ec); // tanh(c)
                float hv = s * th;
                __builtin_nontemporal_store(hv, orow + h);   // streamed, keep L3 for x
                if (last) {
                    out[TBH + bb * H_SZ + h] = hv;                  // h_last
                    out[TBH + B_SZ * H_SZ + bb * H_SZ + h] = cv;    // c_last
                }
            }
        }
    }
}

extern "C" void kernel_launch(void* const* d_in, const int* in_sizes, int n_in,
                              void* d_out, int out_size, void* d_ws, size_t ws_size,
                              hipStream_t stream) {
    const float* x    = (const float*)d_in[0];
    const float* h0   = (const float*)d_in[1];
    const float* c0   = (const float*)d_in[2];
    const float* W_fi = (const float*)d_in[3];
    const float* b_fi = (const float*)d_in[4];
    const float* W_fh = (const float*)d_in[5];
    const float* b_fh = (const float*)d_in[6];
    float* out = (float*)d_out;

    unsigned short* Wb = (unsigned short*)d_ws;               // 65536 bf16 = 128 KB
    float* gb = (float*)((char*)d_ws + 131072);               // 16384 fp32 = 64 KB

    hipLaunchKernelGGL(prep_kernel, dim3(B_SZ), dim3(H_SZ), 0, stream,
                       h0, W_fi, b_fi, W_fh, b_fh, Wb, gb);
    hipLaunchKernelGGL(lstm_main, dim3(M_SZ / 128 * 4), dim3(256), 0, stream,
                       x, Wb, gb, c0, out);
}